// Round 13
// baseline (1146.157 us; speedup 1.0000x reference)
//
#include <hip/hip_runtime.h>
#include <hip/hip_bf16.h>

#define HID 512
#define EMB 512
#define KTOP 8
#define BM 64
#define THREADS 1024
#define POWN (512 * 512)   // elements per 512x512 matrix

typedef __attribute__((ext_vector_type(8))) short bf16x8;
typedef __attribute__((ext_vector_type(4))) float f32x4;
typedef __attribute__((ext_vector_type(4))) unsigned u32x4;

// ---- manual bf16 conversion (RNE) ----------------------------------------
__device__ __forceinline__ short f2bf(float f) {
    unsigned u = __builtin_bit_cast(unsigned, f);
    u += 0x7fffu + ((u >> 16) & 1u);
    return (short)(u >> 16);
}
__device__ __forceinline__ float bf2f(short s) {
    unsigned u = ((unsigned)(unsigned short)s) << 16;
    return __builtin_bit_cast(float, u);
}
__device__ __forceinline__ unsigned cvtpk2(float x, float y) {
    return ((unsigned)(unsigned short)f2bf(x)) |
           (((unsigned)(unsigned short)f2bf(y)) << 16);
}
__device__ __forceinline__ bf16x8 pack8(f32x4 a, f32x4 b) {
    u32x4 r = {cvtpk2(a[0], a[1]), cvtpk2(a[2], a[3]),
               cvtpk2(b[0], b[1]), cvtpk2(b[2], b[3])};
    return __builtin_bit_cast(bf16x8, r);
}
__device__ __forceinline__ void split_bf(float w, short& hi, short& lo) {
    hi = f2bf(w);
    lo = f2bf(w - bf2f(hi));
}

// ---------------------------------------------------------------------------
// Kernel 0: split Wa into hi/lo bf16 (RM + transposed); Ua -> bf16 RM.
// (hi/lo needed only for the accurate power chain; main kernel uses hi only.)
__global__ void prep_kernel(const float* __restrict__ Wa, const float* __restrict__ Ua,
                            short* __restrict__ hiRM, short* __restrict__ loRM,
                            short* __restrict__ hiT, short* __restrict__ loT,
                            short* __restrict__ ua_b) {
    int i = blockIdx.x * blockDim.x + threadIdx.x;
    if (i >= POWN) return;
    int r = i >> 9, c = i & 511;
    short hi, lo;
    split_bf(Wa[i], hi, lo);
    hiRM[i] = hi; loRM[i] = lo;
    hiT[c * 512 + r] = hi;
    loT[c * 512 + r] = lo;
    ua_b[i] = f2bf(Ua[i]);
}

__device__ __forceinline__ int sel4(int4 v, int i) {
    int r = v.x;
    if (i == 1) r = v.y;
    if (i == 2) r = v.z;
    if (i == 3) r = v.w;
    return r;
}

// ---------------------------------------------------------------------------
// Kernel 1: matrix-power products (3-pass split bf16 — keeps powers ~2^-17).
__global__ __launch_bounds__(256)
void powmul_kernel(short* __restrict__ hiRM, short* __restrict__ loRM,
                   short* __restrict__ hiT, short* __restrict__ loT,
                   int4 aS, int4 bS, int4 dS) {
    const int p = blockIdx.z;
    const int as = sel4(aS, p), bs = sel4(bS, p), ds = sel4(dS, p);
    const short* Ah = hiRM + (size_t)as * POWN;
    const short* Al = loRM + (size_t)as * POWN;
    const short* Bh = hiT + (size_t)bs * POWN;
    const short* Bl = loT + (size_t)bs * POWN;

    const int tid = threadIdx.x, lane = tid & 63, w = tid >> 6;
    const int l15 = lane & 15, lg = lane >> 4;
    const int row = blockIdx.x * 64 + w * 16 + l15;
    const int colb = blockIdx.y * 64;

    f32x4 acc[4];
#pragma unroll
    for (int nf = 0; nf < 4; ++nf) acc[nf] = (f32x4){0.f, 0.f, 0.f, 0.f};

    for (int ch = 0; ch < 16; ++ch) {
        const int e0 = ch * 32 + lg * 8;
        bf16x8 ah = *(const bf16x8*)(Ah + row * 512 + e0);
        bf16x8 al = *(const bf16x8*)(Al + row * 512 + e0);
#pragma unroll
        for (int nf = 0; nf < 4; ++nf) {
            const int col = colb + nf * 16 + l15;
            bf16x8 bh = *(const bf16x8*)(Bh + col * 512 + e0);
            bf16x8 bl = *(const bf16x8*)(Bl + col * 512 + e0);
            acc[nf] = __builtin_amdgcn_mfma_f32_16x16x32_bf16(ah, bh, acc[nf], 0, 0, 0);
            acc[nf] = __builtin_amdgcn_mfma_f32_16x16x32_bf16(ah, bl, acc[nf], 0, 0, 0);
            acc[nf] = __builtin_amdgcn_mfma_f32_16x16x32_bf16(al, bh, acc[nf], 0, 0, 0);
        }
    }

    short* Dh = hiRM + (size_t)ds * POWN;
    short* Dl = loRM + (size_t)ds * POWN;
#pragma unroll
    for (int nf = 0; nf < 4; ++nf)
#pragma unroll
        for (int j = 0; j < 4; ++j) {
            int rg = blockIdx.x * 64 + w * 16 + lg * 4 + j;
            int cg = colb + nf * 16 + l15;
            short hi, lo;
            split_bf(acc[nf][j], hi, lo);
            Dh[rg * 512 + cg] = hi;
            Dl[rg * 512 + cg] = lo;
            if (ds < 4) {
                hiT[(size_t)ds * POWN + cg * 512 + rg] = hi;
                loT[(size_t)ds * POWN + cg * 512 + rg] = lo;
            }
        }
}

// ---------------------------------------------------------------------------
// Kernel 2: reorder 9 RM bf16 matrices (8 power-hi + Ua) into MFMA-B-fragment
// layout: swz[ch(16)][cb(32)][lane(64)][8]   (lo no longer used by main)
__global__ __launch_bounds__(256)
void swz_pow_kernel(const short* __restrict__ pow_hi, const short* __restrict__ ua_b,
                    short* __restrict__ swz_hi, short* __restrict__ swz_ua) {
    const int m = blockIdx.y;
    const short* src = (m < 8) ? (pow_hi + (size_t)m * POWN) : ua_b;
    short* dst       = (m < 8) ? (swz_hi + (size_t)m * POWN) : swz_ua;

#pragma unroll
    for (int i = 0; i < 8; ++i) {
        int c = blockIdx.x * 2048 + i * 256 + threadIdx.x;
        bf16x8 v = *(const bf16x8*)(src + c * 8);
        int ch = (c >> 2) & 15;
        int lg = c & 3;
        int cb = c >> 10;
        int l15 = (c >> 6) & 15;
        int lane = lg * 16 + l15;
        *(bf16x8*)(dst + ((size_t)(ch * 32 + cb) * 64 + lane) * 8) = v;
    }
}

// ---------------------------------------------------------------------------
// Kernel 3: query f32 -> bf16 in A-fragment layout per 64-row block (proven).
__global__ __launch_bounds__(THREADS)
void q_prep_kernel(const float* __restrict__ query, short* __restrict__ q_sw) {
    __shared__ short q_s[BM * 512];
    const int tid = threadIdx.x;
    const long rbase = (long)blockIdx.x * BM;

#pragma unroll
    for (int i = 0; i < 4; ++i) {
        int idx = tid + i * THREADS;
        int r = idx >> 6, s = idx & 63;
        const float* qp = query + (rbase + r) * HID + s * 8;
        f32x4 a = *(const f32x4*)qp;
        f32x4 b = *(const f32x4*)(qp + 4);
        *(bf16x8*)&q_s[(r * 64 + (s ^ (r & 7))) * 8] = pack8(a, b);
    }
    __syncthreads();
    short* dst = q_sw + (size_t)blockIdx.x * (BM * 512);
#pragma unroll
    for (int i = 0; i < 4; ++i) {
        int d = tid + i * THREADS;
        int l15 = d & 15, lg = (d >> 4) & 3;
        int ch = (d >> 6) & 15, mf = (d >> 10) & 3;
        int r = mf * 16 + l15;
        int s = ch * 4 + lg;
        bf16x8 v = *(const bf16x8*)&q_s[(r * 64 + (s ^ (r & 7))) * 8];
        *(bf16x8*)(dst + (size_t)d * 8) = v;
    }
}

// ---------------------------------------------------------------------------
// Kernel 4: main — R12 structure verbatim; delta: lo pass removed (2 MFMA per
// (mf,nf) instead of 3) + setprio around the K-loop.
__global__ __launch_bounds__(THREADS, 4)
void attn_main_kernel(const float* __restrict__ topics,
                      const float* __restrict__ cov,
                      const short* __restrict__ q_sw,
                      const short* __restrict__ swz_hi,
                      const short* __restrict__ swz_ua,
                      const float* __restrict__ va_w,
                      const float* __restrict__ va_b,
                      float* __restrict__ out_alpha) {
    __shared__ short t_lds[2][BM * 512];     // 2 x 64 KB bf16 double buffer
    __shared__ float scores_s[BM][KTOP];     // 2 KB

    const int tid  = threadIdx.x;
    const int lane = tid & 63;
    const int wn   = tid >> 6;      // 0..15 : cols wn*32 + nf*16 + l15
    const int l15  = lane & 15;
    const int lg   = lane >> 4;
    // XCD-aware bijective swizzle (gridDim.x = 256, divisible by 8)
    const int bid  = blockIdx.x;
    const int blk  = (bid & 7) * (int)(gridDim.x >> 3) + (bid >> 3);
    const long rbase = (long)blk * BM;

    if (tid < BM * KTOP) ((float*)scores_s)[tid] = 0.f;

    float va_reg[2];
#pragma unroll
    for (int nf = 0; nf < 2; ++nf) va_reg[nf] = va_w[wn * 32 + nf * 16 + l15];
    const float vab = va_b[0];

    const short* qbase = q_sw + (size_t)blk * (BM * 512) + lane * 8;
    const int lane8 = lane * 8;

    // prologue: stage step 0 into buf 0
#pragma unroll
    for (int i = 0; i < 4; ++i) {
        int idx = tid + i * THREADS;
        int r = idx >> 6, s = idx & 63;
        const float* tp = topics + ((rbase + r) * KTOP + 0) * EMB + s * 8;
        f32x4 a = *(const f32x4*)tp;
        f32x4 b = *(const f32x4*)(tp + 4);
        *(bf16x8*)&t_lds[0][(r * 64 + (s ^ (r & 7))) * 8] = pack8(a, b);
    }
    __syncthreads();

#pragma unroll 1
    for (int step = 0; step < KTOP; ++step) {
        const int cur = step & 1;

        // stage NEXT step into buf[cur^1] (transient regs only)
        if (step < KTOP - 1) {
#pragma unroll
            for (int i = 0; i < 4; ++i) {
                int idx = tid + i * THREADS;
                int r = idx >> 6, s = idx & 63;
                const float* tp = topics + ((rbase + r) * KTOP + (step + 1)) * EMB + s * 8;
                f32x4 a = *(const f32x4*)tp;
                f32x4 b = *(const f32x4*)(tp + 4);
                *(bf16x8*)&t_lds[cur ^ 1][(r * 64 + (s ^ (r & 7))) * 8] = pack8(a, b);
            }
        }

        const short* wh = swz_hi + (size_t)step * POWN;

        f32x4 acc[4][2];
#pragma unroll
        for (int mf = 0; mf < 4; ++mf)
#pragma unroll
            for (int nf = 0; nf < 2; ++nf) acc[mf][nf] = (f32x4){0.f, 0.f, 0.f, 0.f};

        __builtin_amdgcn_s_setprio(1);
        for (int ch = 0; ch < 16; ++ch) {
            bf16x8 qf[4], tf[4];
#pragma unroll
            for (int mf = 0; mf < 4; ++mf) {
                qf[mf] = *(const bf16x8*)(qbase + (size_t)(mf * 16 + ch) * 512);
                int r = mf * 16 + l15;
                int s = ch * 4 + lg;
                tf[mf] = *(const bf16x8*)&t_lds[cur][(r * 64 + (s ^ (r & 7))) * 8];
            }
#pragma unroll
            for (int nf = 0; nf < 2; ++nf) {
                const size_t off = (size_t)((ch * 32 + wn * 2 + nf) * 512 + lane8);
                bf16x8 bh = *(const bf16x8*)(wh + off);
                bf16x8 bu = *(const bf16x8*)(swz_ua + off);
#pragma unroll
                for (int mf = 0; mf < 4; ++mf) {
                    acc[mf][nf] = __builtin_amdgcn_mfma_f32_16x16x32_bf16(qf[mf], bh, acc[mf][nf], 0, 0, 0);
                    acc[mf][nf] = __builtin_amdgcn_mfma_f32_16x16x32_bf16(tf[mf], bu, acc[mf][nf], 0, 0, 0);
                }
            }
        }
        __builtin_amdgcn_s_setprio(0);

        // ---- epilogue: partial score over this wave's 32 cols ----
        float part[4][4];
#pragma unroll
        for (int mf = 0; mf < 4; ++mf)
#pragma unroll
            for (int j = 0; j < 4; ++j) part[mf][j] = 0.f;
#pragma unroll
        for (int mf = 0; mf < 4; ++mf)
#pragma unroll
            for (int nf = 0; nf < 2; ++nf)
#pragma unroll
                for (int j = 0; j < 4; ++j) {
                    float x = acc[mf][nf][j];
                    float e = __expf(2.f * x);
                    float th = 1.f - 2.f / (e + 1.f);   // tanh(x)
                    part[mf][j] += th * va_reg[nf];
                }
#pragma unroll
        for (int m = 8; m >= 1; m >>= 1)
#pragma unroll
            for (int mf = 0; mf < 4; ++mf)
#pragma unroll
                for (int j = 0; j < 4; ++j)
                    part[mf][j] += __shfl_xor(part[mf][j], m, 64);
        if (l15 == 0) {   // lanes lg=0..3 cover rows mf*16 + lg*4 + j
#pragma unroll
            for (int mf = 0; mf < 4; ++mf)
#pragma unroll
                for (int j = 0; j < 4; ++j)
                    atomicAdd(&scores_s[mf * 16 + lg * 4 + j][step], part[mf][j]);
        }

        __syncthreads();   // buf[cur] reads done AND buf[cur^1] writes done
    }

    // ---- finalize scores, softmax, alphas ----
    if (tid < BM * KTOP) {
        int r = tid >> 3, k = tid & 7;
        scores_s[r][k] = (scores_s[r][k] + vab) * cov[(rbase + r) * KTOP + k];
    }
    __syncthreads();
    if (tid < BM) {
        float mx = scores_s[tid][0];
#pragma unroll
        for (int k = 1; k < KTOP; ++k) mx = fmaxf(mx, scores_s[tid][k]);
        float e[KTOP], sum = 0.f;
#pragma unroll
        for (int k = 0; k < KTOP; ++k) { e[k] = __expf(scores_s[tid][k] - mx); sum += e[k]; }
#pragma unroll
        for (int k = 0; k < KTOP; ++k)
            out_alpha[(rbase + tid) * KTOP + k] = e[k] / sum;
    }
}

// ---------------------------------------------------------------------------
// Kernel 5: mt = sum_k alpha_k * topics[:,k,:]  (streaming; validated).
__global__ __launch_bounds__(256)
void mt_kernel(const float* __restrict__ topics, const float* __restrict__ alphas,
               float* __restrict__ out_mt) {
    int idx = blockIdx.x * 256 + threadIdx.x;   // 524288 threads, 16 f32 each
    int r  = idx >> 5;
    int c0 = (idx & 31) * 16;
    float a[KTOP];
#pragma unroll
    for (int k = 0; k < KTOP; ++k) a[k] = alphas[(size_t)r * KTOP + k];
    const float* tb = topics + (size_t)r * KTOP * EMB + c0;
    f32x4 o[4];
#pragma unroll
    for (int u = 0; u < 4; ++u) o[u] = (f32x4){0.f, 0.f, 0.f, 0.f};
#pragma unroll
    for (int k = 0; k < KTOP; ++k)
#pragma unroll
        for (int u = 0; u < 4; ++u) {
            f32x4 t = *(const f32x4*)(tb + k * EMB + u * 4);
            o[u][0] += a[k] * t[0];
            o[u][1] += a[k] * t[1];
            o[u][2] += a[k] * t[2];
            o[u][3] += a[k] * t[3];
        }
    float* mp = out_mt + (size_t)r * EMB + c0;
#pragma unroll
    for (int u = 0; u < 4; ++u) *(f32x4*)(mp + u * 4) = o[u];
}

extern "C" void kernel_launch(void* const* d_in, const int* in_sizes, int n_in,
                              void* d_out, int out_size, void* d_ws, size_t ws_size,
                              hipStream_t stream) {
    const float* query  = (const float*)d_in[0];
    const float* topics = (const float*)d_in[1];
    const float* cov    = (const float*)d_in[2];
    const float* Ua     = (const float*)d_in[3];
    const float* Wa     = (const float*)d_in[4];
    const float* va     = (const float*)d_in[5];
    const float* vab    = (const float*)d_in[6];

    const int Brows = in_sizes[0] / HID;   // 16384
    const int nblk  = Brows / BM;          // 256

    // ws (shorts): RM hi[8] | RM lo[8] | T hi[4] | T lo[4] | ua RM |
    //              swz hi[8] | swz ua | q_sw    (~35 MB)
    short* pow_hi = (short*)d_ws;
    short* pow_lo = pow_hi + (size_t)8 * POWN;
    short* hiT    = pow_lo + (size_t)8 * POWN;
    short* loT    = hiT + (size_t)4 * POWN;
    short* ua_b   = loT + (size_t)4 * POWN;
    short* swz_hi = ua_b + POWN;
    short* swz_ua = swz_hi + (size_t)8 * POWN;
    short* q_sw   = swz_ua + POWN;

    float* out_mt    = (float*)d_out;
    float* out_alpha = out_mt + (size_t)Brows * EMB;

    prep_kernel<<<(POWN + 255) / 256, 256, 0, stream>>>(Wa, Ua, pow_hi, pow_lo,
                                                        hiT, loT, ua_b);
    // M2 = M1*M1
    powmul_kernel<<<dim3(8, 8, 1), 256, 0, stream>>>(pow_hi, pow_lo, hiT, loT,
        make_int4(0, 0, 0, 0), make_int4(0, 0, 0, 0), make_int4(1, 0, 0, 0));
    // M3 = M2*M1, M4 = M2*M2
    powmul_kernel<<<dim3(8, 8, 2), 256, 0, stream>>>(pow_hi, pow_lo, hiT, loT,
        make_int4(1, 1, 0, 0), make_int4(0, 1, 0, 0), make_int4(2, 3, 0, 0));
    // M5 = M4*M1, M6 = M4*M2, M7 = M3*M4, M8 = M4*M4
    powmul_kernel<<<dim3(8, 8, 4), 256, 0, stream>>>(pow_hi, pow_lo, hiT, loT,
        make_int4(3, 3, 2, 3), make_int4(0, 1, 3, 3), make_int4(4, 5, 6, 7));

    swz_pow_kernel<<<dim3(16, 9), 256, 0, stream>>>(pow_hi, ua_b, swz_hi, swz_ua);
    q_prep_kernel<<<nblk, THREADS, 0, stream>>>(query, q_sw);

    attn_main_kernel<<<nblk, THREADS, 0, stream>>>(topics, cov, q_sw,
                                                   swz_hi, swz_ua,
                                                   va, vab, out_alpha);
    mt_kernel<<<(Brows * EMB / 16) / 256, 256, 0, stream>>>(topics, out_alpha, out_mt);
}

// Round 14
// 420.559 us; speedup vs baseline: 2.7253x; 2.7253x over previous
//
#include <hip/hip_runtime.h>
#include <hip/hip_bf16.h>

#define HID 512
#define EMB 512
#define KTOP 8
#define BM 64
#define THREADS 1024
#define POWN (512 * 512)   // elements per 512x512 matrix

typedef __attribute__((ext_vector_type(8))) short bf16x8;
typedef __attribute__((ext_vector_type(4))) float f32x4;
typedef __attribute__((ext_vector_type(4))) unsigned u32x4;

// ---- manual bf16 conversion (RNE) ----------------------------------------
__device__ __forceinline__ short f2bf(float f) {
    unsigned u = __builtin_bit_cast(unsigned, f);
    u += 0x7fffu + ((u >> 16) & 1u);
    return (short)(u >> 16);
}
__device__ __forceinline__ float bf2f(short s) {
    unsigned u = ((unsigned)(unsigned short)s) << 16;
    return __builtin_bit_cast(float, u);
}
__device__ __forceinline__ unsigned cvtpk2(float x, float y) {
    return ((unsigned)(unsigned short)f2bf(x)) |
           (((unsigned)(unsigned short)f2bf(y)) << 16);
}
__device__ __forceinline__ bf16x8 pack8(f32x4 a, f32x4 b) {
    u32x4 r = {cvtpk2(a[0], a[1]), cvtpk2(a[2], a[3]),
               cvtpk2(b[0], b[1]), cvtpk2(b[2], b[3])};
    return __builtin_bit_cast(bf16x8, r);
}
__device__ __forceinline__ void split_bf(float w, short& hi, short& lo) {
    hi = f2bf(w);
    lo = f2bf(w - bf2f(hi));
}

// ---------------------------------------------------------------------------
// Kernel 0: split Wa into hi/lo bf16 (RM + transposed); Ua -> bf16 RM.
// (hi/lo needed only for the accurate power chain; main kernel uses hi only.)
__global__ void prep_kernel(const float* __restrict__ Wa, const float* __restrict__ Ua,
                            short* __restrict__ hiRM, short* __restrict__ loRM,
                            short* __restrict__ hiT, short* __restrict__ loT,
                            short* __restrict__ ua_b) {
    int i = blockIdx.x * blockDim.x + threadIdx.x;
    if (i >= POWN) return;
    int r = i >> 9, c = i & 511;
    short hi, lo;
    split_bf(Wa[i], hi, lo);
    hiRM[i] = hi; loRM[i] = lo;
    hiT[c * 512 + r] = hi;
    loT[c * 512 + r] = lo;
    ua_b[i] = f2bf(Ua[i]);
}

__device__ __forceinline__ int sel4(int4 v, int i) {
    int r = v.x;
    if (i == 1) r = v.y;
    if (i == 2) r = v.z;
    if (i == 3) r = v.w;
    return r;
}

// ---------------------------------------------------------------------------
// Kernel 1: matrix-power products (3-pass split bf16 — keeps powers ~2^-17).
__global__ __launch_bounds__(256)
void powmul_kernel(short* __restrict__ hiRM, short* __restrict__ loRM,
                   short* __restrict__ hiT, short* __restrict__ loT,
                   int4 aS, int4 bS, int4 dS) {
    const int p = blockIdx.z;
    const int as = sel4(aS, p), bs = sel4(bS, p), ds = sel4(dS, p);
    const short* Ah = hiRM + (size_t)as * POWN;
    const short* Al = loRM + (size_t)as * POWN;
    const short* Bh = hiT + (size_t)bs * POWN;
    const short* Bl = loT + (size_t)bs * POWN;

    const int tid = threadIdx.x, lane = tid & 63, w = tid >> 6;
    const int l15 = lane & 15, lg = lane >> 4;
    const int row = blockIdx.x * 64 + w * 16 + l15;
    const int colb = blockIdx.y * 64;

    f32x4 acc[4];
#pragma unroll
    for (int nf = 0; nf < 4; ++nf) acc[nf] = (f32x4){0.f, 0.f, 0.f, 0.f};

    for (int ch = 0; ch < 16; ++ch) {
        const int e0 = ch * 32 + lg * 8;
        bf16x8 ah = *(const bf16x8*)(Ah + row * 512 + e0);
        bf16x8 al = *(const bf16x8*)(Al + row * 512 + e0);
#pragma unroll
        for (int nf = 0; nf < 4; ++nf) {
            const int col = colb + nf * 16 + l15;
            bf16x8 bh = *(const bf16x8*)(Bh + col * 512 + e0);
            bf16x8 bl = *(const bf16x8*)(Bl + col * 512 + e0);
            acc[nf] = __builtin_amdgcn_mfma_f32_16x16x32_bf16(ah, bh, acc[nf], 0, 0, 0);
            acc[nf] = __builtin_amdgcn_mfma_f32_16x16x32_bf16(ah, bl, acc[nf], 0, 0, 0);
            acc[nf] = __builtin_amdgcn_mfma_f32_16x16x32_bf16(al, bh, acc[nf], 0, 0, 0);
        }
    }

    short* Dh = hiRM + (size_t)ds * POWN;
    short* Dl = loRM + (size_t)ds * POWN;
#pragma unroll
    for (int nf = 0; nf < 4; ++nf)
#pragma unroll
        for (int j = 0; j < 4; ++j) {
            int rg = blockIdx.x * 64 + w * 16 + lg * 4 + j;
            int cg = colb + nf * 16 + l15;
            short hi, lo;
            split_bf(acc[nf][j], hi, lo);
            Dh[rg * 512 + cg] = hi;
            Dl[rg * 512 + cg] = lo;
            if (ds < 4) {
                hiT[(size_t)ds * POWN + cg * 512 + rg] = hi;
                loT[(size_t)ds * POWN + cg * 512 + rg] = lo;
            }
        }
}

// ---------------------------------------------------------------------------
// Kernel 2: reorder 9 RM bf16 matrices (8 power-hi + Ua) into MFMA-B-fragment
// layout: swz[ch(16)][cb(32)][lane(64)][8]
__global__ __launch_bounds__(256)
void swz_pow_kernel(const short* __restrict__ pow_hi, const short* __restrict__ ua_b,
                    short* __restrict__ swz_hi, short* __restrict__ swz_ua) {
    const int m = blockIdx.y;
    const short* src = (m < 8) ? (pow_hi + (size_t)m * POWN) : ua_b;
    short* dst       = (m < 8) ? (swz_hi + (size_t)m * POWN) : swz_ua;

#pragma unroll
    for (int i = 0; i < 8; ++i) {
        int c = blockIdx.x * 2048 + i * 256 + threadIdx.x;
        bf16x8 v = *(const bf16x8*)(src + c * 8);
        int ch = (c >> 2) & 15;
        int lg = c & 3;
        int cb = c >> 10;
        int l15 = (c >> 6) & 15;
        int lane = lg * 16 + l15;
        *(bf16x8*)(dst + ((size_t)(ch * 32 + cb) * 64 + lane) * 8) = v;
    }
}

// ---------------------------------------------------------------------------
// Kernel 3: query f32 -> bf16 in A-fragment layout per 64-row block (proven).
__global__ __launch_bounds__(THREADS)
void q_prep_kernel(const float* __restrict__ query, short* __restrict__ q_sw) {
    __shared__ short q_s[BM * 512];
    const int tid = threadIdx.x;
    const long rbase = (long)blockIdx.x * BM;

#pragma unroll
    for (int i = 0; i < 4; ++i) {
        int idx = tid + i * THREADS;
        int r = idx >> 6, s = idx & 63;
        const float* qp = query + (rbase + r) * HID + s * 8;
        f32x4 a = *(const f32x4*)qp;
        f32x4 b = *(const f32x4*)(qp + 4);
        *(bf16x8*)&q_s[(r * 64 + (s ^ (r & 7))) * 8] = pack8(a, b);
    }
    __syncthreads();
    short* dst = q_sw + (size_t)blockIdx.x * (BM * 512);
#pragma unroll
    for (int i = 0; i < 4; ++i) {
        int d = tid + i * THREADS;
        int l15 = d & 15, lg = (d >> 4) & 3;
        int ch = (d >> 6) & 15, mf = (d >> 10) & 3;
        int r = mf * 16 + l15;
        int s = ch * 4 + lg;
        bf16x8 v = *(const bf16x8*)&q_s[(r * 64 + (s ^ (r & 7))) * 8];
        *(bf16x8*)(dst + (size_t)d * 8) = v;
    }
}

// ---------------------------------------------------------------------------
// Kernel 4: main — R12 structure verbatim; ONE functional delta: W_lo pass
// removed (2 MFMA per (mf,nf)). ch-loop unroll pinned to 1 to keep R12-like
// codegen (R13's spill came from the unroll heuristic flipping). No setprio.
__global__ __launch_bounds__(THREADS, 4)
void attn_main_kernel(const float* __restrict__ topics,
                      const float* __restrict__ cov,
                      const short* __restrict__ q_sw,
                      const short* __restrict__ swz_hi,
                      const short* __restrict__ swz_ua,
                      const float* __restrict__ va_w,
                      const float* __restrict__ va_b,
                      float* __restrict__ out_alpha) {
    __shared__ short t_lds[2][BM * 512];     // 2 x 64 KB bf16 double buffer
    __shared__ float scores_s[BM][KTOP];     // 2 KB

    const int tid  = threadIdx.x;
    const int lane = tid & 63;
    const int wn   = tid >> 6;      // 0..15 : cols wn*32 + nf*16 + l15
    const int l15  = lane & 15;
    const int lg   = lane >> 4;
    // XCD-aware bijective swizzle (gridDim.x = 256, divisible by 8)
    const int bid  = blockIdx.x;
    const int blk  = (bid & 7) * (int)(gridDim.x >> 3) + (bid >> 3);
    const long rbase = (long)blk * BM;

    if (tid < BM * KTOP) ((float*)scores_s)[tid] = 0.f;

    float va_reg[2];
#pragma unroll
    for (int nf = 0; nf < 2; ++nf) va_reg[nf] = va_w[wn * 32 + nf * 16 + l15];
    const float vab = va_b[0];

    const short* qbase = q_sw + (size_t)blk * (BM * 512) + lane * 8;
    const int lane8 = lane * 8;

    // prologue: stage step 0 into buf 0
#pragma unroll
    for (int i = 0; i < 4; ++i) {
        int idx = tid + i * THREADS;
        int r = idx >> 6, s = idx & 63;
        const float* tp = topics + ((rbase + r) * KTOP + 0) * EMB + s * 8;
        f32x4 a = *(const f32x4*)tp;
        f32x4 b = *(const f32x4*)(tp + 4);
        *(bf16x8*)&t_lds[0][(r * 64 + (s ^ (r & 7))) * 8] = pack8(a, b);
    }
    __syncthreads();

#pragma unroll 1
    for (int step = 0; step < KTOP; ++step) {
        const int cur = step & 1;

        // stage NEXT step into buf[cur^1] (transient regs only)
        if (step < KTOP - 1) {
#pragma unroll
            for (int i = 0; i < 4; ++i) {
                int idx = tid + i * THREADS;
                int r = idx >> 6, s = idx & 63;
                const float* tp = topics + ((rbase + r) * KTOP + (step + 1)) * EMB + s * 8;
                f32x4 a = *(const f32x4*)tp;
                f32x4 b = *(const f32x4*)(tp + 4);
                *(bf16x8*)&t_lds[cur ^ 1][(r * 64 + (s ^ (r & 7))) * 8] = pack8(a, b);
            }
        }

        const short* wh = swz_hi + (size_t)step * POWN;

        f32x4 acc[4][2];
#pragma unroll
        for (int mf = 0; mf < 4; ++mf)
#pragma unroll
            for (int nf = 0; nf < 2; ++nf) acc[mf][nf] = (f32x4){0.f, 0.f, 0.f, 0.f};

#pragma unroll 1
        for (int ch = 0; ch < 16; ++ch) {
            bf16x8 qf[4], tf[4];
#pragma unroll
            for (int mf = 0; mf < 4; ++mf) {
                qf[mf] = *(const bf16x8*)(qbase + (size_t)(mf * 16 + ch) * 512);
                int r = mf * 16 + l15;
                int s = ch * 4 + lg;
                tf[mf] = *(const bf16x8*)&t_lds[cur][(r * 64 + (s ^ (r & 7))) * 8];
            }
#pragma unroll
            for (int nf = 0; nf < 2; ++nf) {
                const size_t off = (size_t)((ch * 32 + wn * 2 + nf) * 512 + lane8);
                bf16x8 bh = *(const bf16x8*)(wh + off);
                bf16x8 bu = *(const bf16x8*)(swz_ua + off);
#pragma unroll
                for (int mf = 0; mf < 4; ++mf) {
                    acc[mf][nf] = __builtin_amdgcn_mfma_f32_16x16x32_bf16(qf[mf], bh, acc[mf][nf], 0, 0, 0);
                    acc[mf][nf] = __builtin_amdgcn_mfma_f32_16x16x32_bf16(tf[mf], bu, acc[mf][nf], 0, 0, 0);
                }
            }
        }

        // ---- epilogue: partial score over this wave's 32 cols ----
        float part[4][4];
#pragma unroll
        for (int mf = 0; mf < 4; ++mf)
#pragma unroll
            for (int j = 0; j < 4; ++j) part[mf][j] = 0.f;
#pragma unroll
        for (int mf = 0; mf < 4; ++mf)
#pragma unroll
            for (int nf = 0; nf < 2; ++nf)
#pragma unroll
                for (int j = 0; j < 4; ++j) {
                    float x = acc[mf][nf][j];
                    float e = __expf(2.f * x);
                    float th = 1.f - 2.f / (e + 1.f);   // tanh(x)
                    part[mf][j] += th * va_reg[nf];
                }
#pragma unroll
        for (int m = 8; m >= 1; m >>= 1)
#pragma unroll
            for (int mf = 0; mf < 4; ++mf)
#pragma unroll
                for (int j = 0; j < 4; ++j)
                    part[mf][j] += __shfl_xor(part[mf][j], m, 64);
        if (l15 == 0) {   // lanes lg=0..3 cover rows mf*16 + lg*4 + j
#pragma unroll
            for (int mf = 0; mf < 4; ++mf)
#pragma unroll
                for (int j = 0; j < 4; ++j)
                    atomicAdd(&scores_s[mf * 16 + lg * 4 + j][step], part[mf][j]);
        }

        __syncthreads();   // buf[cur] reads done AND buf[cur^1] writes done
    }

    // ---- finalize scores, softmax, alphas ----
    if (tid < BM * KTOP) {
        int r = tid >> 3, k = tid & 7;
        scores_s[r][k] = (scores_s[r][k] + vab) * cov[(rbase + r) * KTOP + k];
    }
    __syncthreads();
    if (tid < BM) {
        float mx = scores_s[tid][0];
#pragma unroll
        for (int k = 1; k < KTOP; ++k) mx = fmaxf(mx, scores_s[tid][k]);
        float e[KTOP], sum = 0.f;
#pragma unroll
        for (int k = 0; k < KTOP; ++k) { e[k] = __expf(scores_s[tid][k] - mx); sum += e[k]; }
#pragma unroll
        for (int k = 0; k < KTOP; ++k)
            out_alpha[(rbase + tid) * KTOP + k] = e[k] / sum;
    }
}

// ---------------------------------------------------------------------------
// Kernel 5: mt = sum_k alpha_k * topics[:,k,:]  (streaming; validated).
__global__ __launch_bounds__(256)
void mt_kernel(const float* __restrict__ topics, const float* __restrict__ alphas,
               float* __restrict__ out_mt) {
    int idx = blockIdx.x * 256 + threadIdx.x;   // 524288 threads, 16 f32 each
    int r  = idx >> 5;
    int c0 = (idx & 31) * 16;
    float a[KTOP];
#pragma unroll
    for (int k = 0; k < KTOP; ++k) a[k] = alphas[(size_t)r * KTOP + k];
    const float* tb = topics + (size_t)r * KTOP * EMB + c0;
    f32x4 o[4];
#pragma unroll
    for (int u = 0; u < 4; ++u) o[u] = (f32x4){0.f, 0.f, 0.f, 0.f};
#pragma unroll
    for (int k = 0; k < KTOP; ++k)
#pragma unroll
        for (int u = 0; u < 4; ++u) {
            f32x4 t = *(const f32x4*)(tb + k * EMB + u * 4);
            o[u][0] += a[k] * t[0];
            o[u][1] += a[k] * t[1];
            o[u][2] += a[k] * t[2];
            o[u][3] += a[k] * t[3];
        }
    float* mp = out_mt + (size_t)r * EMB + c0;
#pragma unroll
    for (int u = 0; u < 4; ++u) *(f32x4*)(mp + u * 4) = o[u];
}

extern "C" void kernel_launch(void* const* d_in, const int* in_sizes, int n_in,
                              void* d_out, int out_size, void* d_ws, size_t ws_size,
                              hipStream_t stream) {
    const float* query  = (const float*)d_in[0];
    const float* topics = (const float*)d_in[1];
    const float* cov    = (const float*)d_in[2];
    const float* Ua     = (const float*)d_in[3];
    const float* Wa     = (const float*)d_in[4];
    const float* va     = (const float*)d_in[5];
    const float* vab    = (const float*)d_in[6];

    const int Brows = in_sizes[0] / HID;   // 16384
    const int nblk  = Brows / BM;          // 256

    // ws (shorts): RM hi[8] | RM lo[8] | T hi[4] | T lo[4] | ua RM |
    //              swz hi[8] | swz ua | q_sw    (~35 MB)
    short* pow_hi = (short*)d_ws;
    short* pow_lo = pow_hi + (size_t)8 * POWN;
    short* hiT    = pow_lo + (size_t)8 * POWN;
    short* loT    = hiT + (size_t)4 * POWN;
    short* ua_b   = loT + (size_t)4 * POWN;
    short* swz_hi = ua_b + POWN;
    short* swz_ua = swz_hi + (size_t)8 * POWN;
    short* q_sw   = swz_ua + POWN;

    float* out_mt    = (float*)d_out;
    float* out_alpha = out_mt + (size_t)Brows * EMB;

    prep_kernel<<<(POWN + 255) / 256, 256, 0, stream>>>(Wa, Ua, pow_hi, pow_lo,
                                                        hiT, loT, ua_b);
    // M2 = M1*M1
    powmul_kernel<<<dim3(8, 8, 1), 256, 0, stream>>>(pow_hi, pow_lo, hiT, loT,
        make_int4(0, 0, 0, 0), make_int4(0, 0, 0, 0), make_int4(1, 0, 0, 0));
    // M3 = M2*M1, M4 = M2*M2
    powmul_kernel<<<dim3(8, 8, 2), 256, 0, stream>>>(pow_hi, pow_lo, hiT, loT,
        make_int4(1, 1, 0, 0), make_int4(0, 1, 0, 0), make_int4(2, 3, 0, 0));
    // M5 = M4*M1, M6 = M4*M2, M7 = M3*M4, M8 = M4*M4
    powmul_kernel<<<dim3(8, 8, 4), 256, 0, stream>>>(pow_hi, pow_lo, hiT, loT,
        make_int4(3, 3, 2, 3), make_int4(0, 1, 3, 3), make_int4(4, 5, 6, 7));

    swz_pow_kernel<<<dim3(16, 9), 256, 0, stream>>>(pow_hi, ua_b, swz_hi, swz_ua);
    q_prep_kernel<<<nblk, THREADS, 0, stream>>>(query, q_sw);

    attn_main_kernel<<<nblk, THREADS, 0, stream>>>(topics, cov, q_sw,
                                                   swz_hi, swz_ua,
                                                   va, vab, out_alpha);
    mt_kernel<<<(Brows * EMB / 16) / 256, 256, 0, stream>>>(topics, out_alpha, out_mt);
}